// Round 5
// baseline (615.766 us; speedup 1.0000x reference)
//
#include <hip/hip_runtime.h>
#include <cstdint>
#include <cstddef>

// ============================================================================
// VQ-VAE encode: conv3x3(SAME) -> linear (folded) -> argmin over 8192 codes.
//
// Round 5:
//   fold5_k : W2 fold with e-tile 8/block, scalar (wave-uniform) conv_w reads.
//   convm2_k: conv MFMA with whole image resident in LDS (hi/lo fp16 planes,
//             XOR-swizzled, zero-row halo), B-chunks 8 KB double-buffered,
//             ONE barrier per iter, fused A2 (fp16 y) output.
//             Dynamic LDS 149,504 B -> guarded by MaxSharedMemoryPerBlock.
//   screen3_k: BK=64 double-buffered MFMA screen (64 KB static LDS),
//             XOR-swizzled, 4 iters x 1 barrier -> 128 candidates/row.
//   refine2_k: exact fp32 re-score of candidates within 0.25 of screen min.
// Fallback (LDS-limited device): round-4 verified path (packlat+convm+packhi).
// ============================================================================

#define CIN_  512
#define E_    4608
#define M_    16384

typedef _Float16 half4_t __attribute__((ext_vector_type(4)));
typedef _Float16 half8_t __attribute__((ext_vector_type(8)));
typedef float f32x4 __attribute__((ext_vector_type(4)));

#define GLOAD_LDS16(gptr, lptr)                                         \
    __builtin_amdgcn_global_load_lds(                                   \
        (const __attribute__((address_space(1))) unsigned int*)(gptr),  \
        (__attribute__((address_space(3))) unsigned int*)(lptr), 16, 0, 0)

// ---------------- transpose ----------------
__global__ void tkern(const float* __restrict__ src, float* __restrict__ dst,
                      int R, int C) {
    __shared__ float t[32][33];
    int c = blockIdx.x * 32 + threadIdx.x;
    int r = blockIdx.y * 32 + threadIdx.y;
    if (r < R && c < C) t[threadIdx.y][threadIdx.x] = src[(size_t)r * C + c];
    __syncthreads();
    int rr = blockIdx.x * 32 + threadIdx.y;
    int cc = blockIdx.y * 32 + threadIdx.x;
    if (rr < C && cc < R) dst[(size_t)rr * R + cc] = t[threadIdx.x][threadIdx.y];
}

// ---------------- fold: W2x[plane][tap][d][512c] fp16 hi/lo ----------------
// e-tile 8 per block; conv_w reads are wave-uniform -> scalar loads.
__global__ __launch_bounds__(256) void fold5_k(const float* __restrict__ conv_w,
                                               const float* __restrict__ lwT,
                                               _Float16* __restrict__ W2x) {
    int e0 = blockIdx.x * 8;
    int d = threadIdx.x;
    float acc[8];
    #pragma unroll
    for (int j = 0; j < 8; ++j) acc[j] = 0.f;
    for (int co = 0; co < 256; ++co) {
        float lw = lwT[co * 256 + d];                 // coalesced vector load
        const float* cwr = conv_w + (size_t)co * E_ + e0;   // uniform -> s_load
        #pragma unroll
        for (int j = 0; j < 8; ++j) acc[j] += cwr[j] * lw;
    }
    #pragma unroll
    for (int j = 0; j < 8; ++j) {
        int e = e0 + j;
        int c = e / 9, t9 = e - c * 9;
        _Float16 h = (_Float16)acc[j];
        _Float16 l = (_Float16)(acc[j] - (float)h);
        W2x[((size_t)(t9 * 256 + d)) * 512 + c] = h;
        W2x[((size_t)((9 + t9) * 256 + d)) * 512 + c] = l;
    }
}

__global__ void bias_k(const float* __restrict__ lwT, const float* __restrict__ conv_b,
                       const float* __restrict__ lin_b, float* __restrict__ b2) {
    int d = threadIdx.x;
    float acc = lin_b[d];
    for (int co = 0; co < 256; ++co) acc += lwT[co * 256 + d] * conv_b[co];
    b2[d] = acc;
}

__global__ void embsq_k(const float* __restrict__ emb, float* __restrict__ esq) {
    int w = threadIdx.x >> 6, lane = threadIdx.x & 63;
    int k = blockIdx.x * 4 + w;
    const float* row = emb + (size_t)k * 256;
    float s = 0.f;
    #pragma unroll
    for (int i = 0; i < 4; ++i) { float v = row[lane + 64 * i]; s += v * v; }
    #pragma unroll
    for (int m = 32; m >= 1; m >>= 1) s += __shfl_xor(s, m, 64);
    if (lane == 0) esq[k] = s;
}

// ---------------- conv MFMA v2: image-resident LDS ----------------
// grid 512: block = (img = bx>>1, n0 = (bx&1)*128). 4 waves (2 pix-half x 2 d-half).
// LDS: Ap [2 planes][65 rows][512 c] fp16 swizzled (row 64 = zeros), 133,120 B
//      Bb 2 x 8 KB double-buffered B chunks [128 d][32 c]          -> 149,504 B
#define CONV2_LDS 149504
__global__ __launch_bounds__(256) void convm2_k(
    const float* __restrict__ lat, const _Float16* __restrict__ W2x,
    const float* __restrict__ b2, float* __restrict__ yb,
    _Float16* __restrict__ A2) {
    extern __shared__ char sm[];
    _Float16* Ap = (_Float16*)sm;                 // halves; plane stride 65*512
    char* Bb = sm + 133120;                       // 2 x 8192 B
    int img = blockIdx.x >> 1, n0 = (blockIdx.x & 1) * 128;
    int tid = threadIdx.x, w = tid >> 6, lane = tid & 63;
    int wm = w & 1, wn = w >> 1;
    int fr = lane & 15, fq = lane >> 4;

    // ---- stage A once: coalesced reads (lanes = pixels), b128 LDS writes ----
    {
        int p = tid & 63, cg = tid >> 6;
        const float* src = lat + (size_t)img * 512 * 64 + p;
        #pragma unroll 4
        for (int c8 = 0; c8 < 16; ++c8) {
            int cbase = cg * 128 + c8 * 8;
            half8_t hh, ll;
            #pragma unroll
            for (int j = 0; j < 8; ++j) {
                float v = src[(size_t)(cbase + j) * 64];
                _Float16 h = (_Float16)v;
                hh[j] = h; ll[j] = (_Float16)(v - (float)h);
            }
            int blk = cbase >> 3;
            int boff = p * 1024 + ((blk ^ (p & 7)) << 4);   // bytes
            *(half8_t*)((char*)Ap + boff) = hh;
            *(half8_t*)((char*)Ap + 66560 + boff) = ll;
        }
        // zero halo row p=64 (both planes): 512 halves = 256 uints each
        ((unsigned int*)((char*)Ap + 64 * 1024))[tid] = 0u;
        ((unsigned int*)((char*)Ap + 66560 + 64 * 1024))[tid] = 0u;
    }

    // B staging slots (wave-ordered; source XOR-permuted to kill conflicts)
    int n_0 = w * 2048 + lane * 16;
    int n_1 = n_0 + 1024;
    int dB0 = n_0 >> 6, dB1 = n_1 >> 6;
    int cbl0 = ((n_0 >> 4) & 3) ^ (dB0 & 3);
    int cbl1 = ((n_1 >> 4) & 3) ^ (dB1 & 3);

    f32x4 acc[2][4];
    #pragma unroll
    for (int s = 0; s < 2; ++s)
        #pragma unroll
        for (int t = 0; t < 4; ++t)
            #pragma unroll
            for (int r = 0; r < 4; ++r) acc[s][t][r] = 0.f;

    auto stageB = [&](int idx, int buf) {
        int tap = idx >> 5, cc = (idx >> 1) & 15, bpl = idx & 1;
        const _Float16* base =
            W2x + ((size_t)((bpl * 9 + tap) * 256 + n0)) * 512 + cc * 32;
        GLOAD_LDS16(base + (size_t)dB0 * 512 + cbl0 * 8, Bb + buf * 8192 + n_0);
        GLOAD_LDS16(base + (size_t)dB1 * 512 + cbl1 * 8, Bb + buf * 8192 + n_1);
    };
    stageB(0, 0);

    half8_t ah[2], al[2];
    for (int idx = 0; idx < 288; ++idx) {
        int tap = idx >> 5, cc = (idx >> 1) & 15, bpl = idx & 1;
        __syncthreads();                       // drains prefetch (vmcnt) + LDS
        int nx = (idx + 1 < 288) ? idx + 1 : 287;
        stageB(nx, (idx + 1) & 1);
        const char* bbase = Bb + (idx & 1) * 8192;
        half8_t bf[4];
        #pragma unroll
        for (int t = 0; t < 4; ++t) {
            int dd = wn * 64 + t * 16 + fr;
            bf[t] = *(const half8_t*)(bbase + dd * 64 + ((fq ^ (dd & 3)) << 4));
        }
        if (bpl == 0) {
            int dy = tap / 3 - 1, dx = tap - (tap / 3) * 3 - 1;
            #pragma unroll
            for (int s = 0; s < 2; ++s) {
                int pm = wm * 32 + s * 16 + fr;
                int ih = (pm >> 3) + dy, iw = (pm & 7) + dx;
                int pp = (((unsigned)ih < 8u) && ((unsigned)iw < 8u))
                             ? (ih * 8 + iw) : 64;
                int boff = pp * 1024 + (((cc * 4 + fq) ^ (pp & 7)) << 4);
                ah[s] = *(const half8_t*)((const char*)Ap + boff);
                al[s] = *(const half8_t*)((const char*)Ap + 66560 + boff);
            }
            #pragma unroll
            for (int s = 0; s < 2; ++s)
                #pragma unroll
                for (int t = 0; t < 4; ++t) {
                    acc[s][t] = __builtin_amdgcn_mfma_f32_16x16x32_f16(
                        ah[s], bf[t], acc[s][t], 0, 0, 0);
                    acc[s][t] = __builtin_amdgcn_mfma_f32_16x16x32_f16(
                        al[s], bf[t], acc[s][t], 0, 0, 0);
                }
        } else {
            #pragma unroll
            for (int s = 0; s < 2; ++s)
                #pragma unroll
                for (int t = 0; t < 4; ++t)
                    acc[s][t] = __builtin_amdgcn_mfma_f32_16x16x32_f16(
                        ah[s], bf[t], acc[s][t], 0, 0, 0);
        }
    }

    // epilogue: +bias, write yb fp32 and A2 fp16 (fused pack)
    float bv[4];
    #pragma unroll
    for (int t = 0; t < 4; ++t) bv[t] = b2[n0 + wn * 64 + t * 16 + fr];
    #pragma unroll
    for (int s = 0; s < 2; ++s)
        #pragma unroll
        for (int r = 0; r < 4; ++r) {
            int p = wm * 32 + s * 16 + fq * 4 + r;
            size_t gm = (size_t)img * 64 + p;
            #pragma unroll
            for (int t = 0; t < 4; ++t) {
                int d = n0 + wn * 64 + t * 16 + fr;
                float val = acc[s][t][r] + bv[t];
                yb[gm * 256 + d] = val;
                A2[gm * 256 + d] = (_Float16)val;
            }
        }
}

// ---------------- fp32 -> fp16 hi pack ----------------
__global__ void packhi_k(const float* __restrict__ x, _Float16* __restrict__ o) {
    int i = blockIdx.x * 256 + threadIdx.x;
    float4 v = *(const float4*)(x + (size_t)i * 4);
    half4_t h = {(_Float16)v.x, (_Float16)v.y, (_Float16)v.z, (_Float16)v.w};
    *(half4_t*)(o + (size_t)i * 4) = h;
}

// ---------------- MFMA screen v3: BK=64, double-buffered ----------------
// grid (128 m-tiles, 64 n-tiles), 256 thr = 4 waves (2x2 of 64x64).
__global__ __launch_bounds__(256) void screen3_k(
    const _Float16* __restrict__ A2, const _Float16* __restrict__ B2,
    const float* __restrict__ esq, float* __restrict__ ps2, int* __restrict__ pi2) {
    __shared__ _Float16 la[2][128 * 64];
    __shared__ _Float16 lb[2][128 * 64];
    int m0 = blockIdx.x * 128, n0 = blockIdx.y * 128;
    int tid = threadIdx.x, w = tid >> 6, lane = tid & 63;
    int wm = w & 1, wn = w >> 1;
    int fr = lane & 15, fq = lane >> 4;

    int rows[4], colh[4], slot[4];
    #pragma unroll
    for (int i = 0; i < 4; ++i) {
        int n = w * 4096 + i * 1024 + lane * 16;
        slot[i] = n;
        rows[i] = n >> 7;
        colh[i] = ((((n >> 4) & 7) ^ (rows[i] & 7))) * 8;   // logical col (halves)
    }
    auto stage = [&](int kt, int buf) {
        int ko = kt * 64;
        #pragma unroll
        for (int i = 0; i < 4; ++i) {
            GLOAD_LDS16(A2 + (size_t)(m0 + rows[i]) * 256 + ko + colh[i],
                        (char*)la[buf] + slot[i]);
            GLOAD_LDS16(B2 + (size_t)(n0 + rows[i]) * 256 + ko + colh[i],
                        (char*)lb[buf] + slot[i]);
        }
    };
    f32x4 acc[4][4];
    #pragma unroll
    for (int s = 0; s < 4; ++s)
        #pragma unroll
        for (int t = 0; t < 4; ++t)
            #pragma unroll
            for (int r = 0; r < 4; ++r) acc[s][t][r] = 0.f;

    stage(0, 0);
    for (int kt = 0; kt < 4; ++kt) {
        __syncthreads();
        int nx = (kt + 1 < 4) ? kt + 1 : 3;
        stage(nx, (kt + 1) & 1);
        const char* lap = (const char*)la[kt & 1];
        const char* lbp = (const char*)lb[kt & 1];
        #pragma unroll
        for (int kk = 0; kk < 2; ++kk) {
            half8_t af[4], bf[4];
            #pragma unroll
            for (int s = 0; s < 4; ++s) {
                int row = wm * 64 + s * 16 + fr;
                af[s] = *(const half8_t*)(lap + row * 128 +
                          (((kk * 4 + fq) ^ (row & 7)) << 4));
            }
            #pragma unroll
            for (int t = 0; t < 4; ++t) {
                int row = wn * 64 + t * 16 + fr;
                bf[t] = *(const half8_t*)(lbp + row * 128 +
                          (((kk * 4 + fq) ^ (row & 7)) << 4));
            }
            #pragma unroll
            for (int s = 0; s < 4; ++s)
                #pragma unroll
                for (int t = 0; t < 4; ++t)
                    acc[s][t] = __builtin_amdgcn_mfma_f32_16x16x32_f16(
                        af[s], bf[t], acc[s][t], 0, 0, 0);
        }
    }

    float esv[4];
    #pragma unroll
    for (int t = 0; t < 4; ++t) esv[t] = esq[n0 + wn * 64 + t * 16 + fr];
    int colIdx = blockIdx.y * 2 + wn;
    #pragma unroll
    for (int s = 0; s < 4; ++s) {
        #pragma unroll
        for (int r = 0; r < 4; ++r) {
            float best = 3.4e38f; int bidx = 0x7fffffff;
            #pragma unroll
            for (int t = 0; t < 4; ++t) {
                float sc = esv[t] - 2.f * acc[s][t][r];
                int k = n0 + wn * 64 + t * 16 + fr;
                if (sc < best || (sc == best && k < bidx)) { best = sc; bidx = k; }
            }
            #pragma unroll
            for (int msk = 1; msk <= 8; msk <<= 1) {
                float so = __shfl_xor(best, msk, 64);
                int ko2 = __shfl_xor(bidx, msk, 64);
                if (so < best || (so == best && ko2 < bidx)) { best = so; bidx = ko2; }
            }
            if (fr == 0) {
                int m = m0 + wm * 64 + s * 16 + fq * 4 + r;
                ps2[(size_t)m * 128 + colIdx] = best;
                pi2[(size_t)m * 128 + colIdx] = bidx;
            }
        }
    }
}

// ---------------- exact fp32 refine ----------------
__global__ __launch_bounds__(256) void refine2_k(
    const float* __restrict__ y, const float* __restrict__ emb,
    const float* __restrict__ esq, const float* __restrict__ ps2,
    const int* __restrict__ pi2, int* __restrict__ out) {
    int lane = threadIdx.x & 63;
    int m = blockIdx.x * 4 + (threadIdx.x >> 6);
    float4 yv = *(const float4*)(y + (size_t)m * 256 + lane * 4);
    float sc_[2]; int kc_[2];
    #pragma unroll
    for (int i = 0; i < 2; ++i) {
        sc_[i] = ps2[(size_t)m * 128 + lane * 2 + i];
        kc_[i] = pi2[(size_t)m * 128 + lane * 2 + i];
    }
    float s0 = fminf(sc_[0], sc_[1]);
    #pragma unroll
    for (int msk = 1; msk <= 32; msk <<= 1) s0 = fminf(s0, __shfl_xor(s0, msk, 64));
    float thr = s0 + 0.25f;
    float best = 3.4e38f; int bk = 0x7fffffff;
    for (int c = 0; c < 128; ++c) {
        float scc = __shfl(sc_[c & 1], c >> 1, 64);
        if (scc <= thr) {            // wave-uniform
            int k = __shfl(kc_[c & 1], c >> 1, 64);
            float4 ev = *(const float4*)(emb + (size_t)k * 256 + lane * 4);
            float d = yv.x * ev.x + yv.y * ev.y + yv.z * ev.z + yv.w * ev.w;
            #pragma unroll
            for (int msk = 1; msk <= 32; msk <<= 1) d += __shfl_xor(d, msk, 64);
            float sx = esq[k] - 2.f * d;
            if (sx < best || (sx == best && k < bk)) { best = sx; bk = k; }
        }
    }
    if (lane == 0) out[m] = bk;
}

// ================= fallback conv path (round-4, verified) =================
__global__ __launch_bounds__(256) void packlat_k(const float* __restrict__ lat,
                                                 _Float16* __restrict__ Xnp) {
    int b = blockIdx.x, t = threadIdx.x;
    __shared__ float lt[128][65];
    const float* src = lat + (size_t)b * 512 * 64;
    _Float16* dst = Xnp + (size_t)b * 64 * 1024;
    for (int c0 = 0; c0 < 512; c0 += 128) {
        __syncthreads();
        #pragma unroll
        for (int j = 0; j < 8; ++j) {
            int f4 = t + j * 256;
            int cc = f4 >> 4, p4 = (f4 & 15) * 4;
            float4 v = *(const float4*)(src + (size_t)(c0 + cc) * 64 + p4);
            lt[cc][p4] = v.x; lt[cc][p4 + 1] = v.y;
            lt[cc][p4 + 2] = v.z; lt[cc][p4 + 3] = v.w;
        }
        __syncthreads();
        int pix = t >> 2, cr = (t & 3) * 32;
        #pragma unroll
        for (int q = 0; q < 4; ++q) {
            half8_t hh, ll;
            #pragma unroll
            for (int j = 0; j < 8; ++j) {
                float v = lt[cr + q * 8 + j][pix];
                _Float16 h = (_Float16)v;
                hh[j] = h; ll[j] = (_Float16)(v - (float)h);
            }
            *(half8_t*)(dst + (size_t)pix * 1024 + c0 + cr + q * 8) = hh;
            *(half8_t*)(dst + (size_t)pix * 1024 + 512 + c0 + cr + q * 8) = ll;
        }
    }
}

__global__ __launch_bounds__(256) void convm_k(
    const _Float16* __restrict__ Xnp, const _Float16* __restrict__ W2x,
    const float* __restrict__ b2, const _Float16* __restrict__ zp,
    float* __restrict__ yb) {
    int m0 = blockIdx.x * 128, n0 = blockIdx.y * 128;
    int tid = threadIdx.x, w = tid >> 6, lane = tid & 63;
    int wm = w & 1, wn = w >> 1;
    int fr = lane & 15, fq = lane >> 4;
    __shared__ _Float16 la[128 * 32];
    __shared__ _Float16 lb[128 * 32];
    f32x4 acc[4][4];
    #pragma unroll
    for (int s = 0; s < 4; ++s)
        #pragma unroll
        for (int t = 0; t < 4; ++t)
            #pragma unroll
            for (int r = 0; r < 4; ++r) acc[s][t][r] = 0.f;
    int s0 = w * 2048 + lane * 16;
    int s1 = s0 + 1024;
    int row0 = s0 >> 6, ch0 = (s0 & 63) >> 1;
    int row1 = s1 >> 6, ch1 = (s1 & 63) >> 1;
    int b0_ = (m0 + row0) >> 6, i0 = (m0 + row0) & 63, h0 = i0 >> 3, x0 = i0 & 7;
    int b1_ = (m0 + row1) >> 6, i1 = (m0 + row1) & 63, h1 = i1 >> 3, x1 = i1 & 7;
    for (int seg = 0; seg < 3; ++seg) {
        int apl = (seg == 2) ? 1 : 0;
        int bpl = (seg == 1) ? 1 : 0;
        for (int tap = 0; tap < 9; ++tap) {
            int dy = tap / 3 - 1, dx = tap % 3 - 1;
            int ih0 = h0 + dy, iw0 = x0 + dx;
            int ih1 = h1 + dy, iw1 = x1 + dx;
            bool v0 = ((unsigned)ih0 < 8u) && ((unsigned)iw0 < 8u);
            bool v1 = ((unsigned)ih1 < 8u) && ((unsigned)iw1 < 8u);
            const _Float16* Ab0 = v0
                ? Xnp + (((size_t)(b0_ * 64 + ih0 * 8 + iw0) * 2 + apl) * 512 + ch0)
                : zp + ch0;
            const _Float16* Ab1 = v1
                ? Xnp + (((size_t)(b1_ * 64 + ih1 * 8 + iw1) * 2 + apl) * 512 + ch1)
                : zp + ch1;
            const _Float16* Bb0 =
                W2x + ((size_t)((bpl * 9 + tap) * 256 + n0 + row0) * 512 + ch0);
            const _Float16* Bb1 =
                W2x + ((size_t)((bpl * 9 + tap) * 256 + n0 + row1) * 512 + ch1);
            for (int c0 = 0; c0 < 512; c0 += 32) {
                __syncthreads();
                GLOAD_LDS16(Ab0 + c0, (char*)la + s0);
                GLOAD_LDS16(Ab1 + c0, (char*)la + s1);
                GLOAD_LDS16(Bb0 + c0, (char*)lb + s0);
                GLOAD_LDS16(Bb1 + c0, (char*)lb + s1);
                __syncthreads();
                half8_t af[4], bf[4];
                #pragma unroll
                for (int s = 0; s < 4; ++s)
                    af[s] = *(const half8_t*)&la[(wm * 64 + s * 16 + fr) * 32 + fq * 8];
                #pragma unroll
                for (int t = 0; t < 4; ++t)
                    bf[t] = *(const half8_t*)&lb[(wn * 64 + t * 16 + fr) * 32 + fq * 8];
                #pragma unroll
                for (int s = 0; s < 4; ++s)
                    #pragma unroll
                    for (int t = 0; t < 4; ++t)
                        acc[s][t] = __builtin_amdgcn_mfma_f32_16x16x32_f16(
                            af[s], bf[t], acc[s][t], 0, 0, 0);
            }
        }
    }
    float bv[4];
    #pragma unroll
    for (int t = 0; t < 4; ++t) bv[t] = b2[n0 + wn * 64 + t * 16 + fr];
    #pragma unroll
    for (int s = 0; s < 4; ++s)
        #pragma unroll
        for (int r = 0; r < 4; ++r) {
            int m = m0 + wm * 64 + s * 16 + fq * 4 + r;
            #pragma unroll
            for (int t = 0; t < 4; ++t) {
                int d = n0 + wn * 64 + t * 16 + fr;
                yb[(size_t)m * 256 + d] = acc[s][t][r] + bv[t];
            }
        }
}

extern "C" void kernel_launch(void* const* d_in, const int* in_sizes, int n_in,
                              void* d_out, int out_size, void* d_ws, size_t ws_size,
                              hipStream_t stream) {
    const float* latent = (const float*)d_in[0];
    const float* conv_w = (const float*)d_in[1];
    const float* conv_b = (const float*)d_in[2];
    const float* lin_w  = (const float*)d_in[3];
    const float* lin_b  = (const float*)d_in[4];
    const float* emb    = (const float*)d_in[5];
    int* out = (int*)d_out;

    char* W = (char*)d_ws;                           // round-4 layout (proven fit)
    float*    lwT = (float*)(W + 0);                 //   262,144
    float*    b2  = (float*)(W + 262144);            //     1,024
    float*    esq = (float*)(W + 263168);            //    32,768
    float*    yb  = (float*)(W + 295936);            // 16,777,216
    _Float16* W2x = (_Float16*)(W + 17073152);       //  4,718,592
    _Float16* zp  = (_Float16*)(W + 21791744);       //     1,024
    _Float16* Xnp = (_Float16*)(W + 21792768);       // 33,554,432 (fallback only)
    _Float16* A2  = (_Float16*)(W + 21792768);       //  8,388,608 (alias)
    _Float16* B2  = (_Float16*)(W + 30181376);       //  4,194,304
    float*    ps2 = (float*)(W + 34375680);          //  8,388,608
    int*      pi2 = (int*)(W + 42764288);            //  8,388,608 -> 51,152,896

    int dev = 0;
    (void)hipGetDevice(&dev);
    int maxShm = 0;
    bool fastConv =
        (hipDeviceGetAttribute(&maxShm, hipDeviceAttributeMaxSharedMemoryPerBlock,
                               dev) == hipSuccess) && (maxShm >= CONV2_LDS);

    dim3 t32(32, 32);
    tkern<<<dim3(8, 8), t32, 0, stream>>>(lin_w, lwT, 256, 256);
    bias_k<<<1, 256, 0, stream>>>(lwT, conv_b, lin_b, b2);
    embsq_k<<<2048, 256, 0, stream>>>(emb, esq);
    fold5_k<<<576, 256, 0, stream>>>(conv_w, lwT, W2x);
    packhi_k<<<2048, 256, 0, stream>>>(emb, B2);     // 8192x256

    if (fastConv) {
        convm2_k<<<512, 256, CONV2_LDS, stream>>>(latent, W2x, b2, yb, A2);
    } else {
        hipMemsetAsync(zp, 0, 1024, stream);
        packlat_k<<<256, 256, 0, stream>>>(latent, Xnp);
        convm_k<<<dim3(128, 2), 256, 0, stream>>>(Xnp, W2x, b2, zp, yb);
        packhi_k<<<4096, 256, 0, stream>>>(yb, A2);  // 16384x256
    }
    screen3_k<<<dim3(128, 64), 256, 0, stream>>>(A2, B2, esq, ps2, pi2);
    refine2_k<<<4096, 256, 0, stream>>>(yb, emb, esq, ps2, pi2, out);
}

// Round 6
// 520.735 us; speedup vs baseline: 1.1825x; 1.1825x over previous
//
#include <hip/hip_runtime.h>
#include <cstdint>
#include <cstddef>

// ============================================================================
// VQ-VAE encode: conv3x3(SAME) -> linear (folded) -> argmin over 8192 codes.
//
// Round 6: bank-conflict-free LDS via slot-permuted global_load_lds.
//   Key insight (R4/R5 post-mortem): row strides that are multiples of 128 B
//   make LDS banks independent of the row, so MFMA fragment reads (16 lanes =
//   16 rows, same column) were ~8-way conflicted regardless of block-XOR
//   swizzles. Fix: permute the GATHER so LDS slot s holds
//   (row=s>>2, quad=(s&3)^((s>>3)&3))  [BK=32], read at r*64+(q^((r>>1)&3))*16
//   -> every consecutive lane-octet covers 8 distinct bank-quads.
//   convm4_k: per (tap,chunk) stage A-hi/A-lo/B-hi/B-lo (32 KB), run 3 hi/lo
//     segments (AhBh, AhBl, AlBh) = 48 MFMA/wave per staging; 1 barrier/iter,
//     double-buffered 64 KB LDS. Halo rows -> zero page. 144 iters.
//   screen4_k: BK=64, same slot-permute ((s&7)^(r&7)), double-buffered,
//     4 iters x 1 barrier -> 128 candidates/row.
//   refine2_k: exact fp32 re-score of candidates within 0.25 of screen min.
// argmin tie-break everywhere: strict < with smaller-index preference.
// ============================================================================

#define CIN_  512
#define E_    4608
#define M_    16384

typedef _Float16 half4_t __attribute__((ext_vector_type(4)));
typedef _Float16 half8_t __attribute__((ext_vector_type(8)));
typedef float f32x4 __attribute__((ext_vector_type(4)));

#define GLOAD_LDS16(gptr, lptr)                                         \
    __builtin_amdgcn_global_load_lds(                                   \
        (const __attribute__((address_space(1))) unsigned int*)(gptr),  \
        (__attribute__((address_space(3))) unsigned int*)(lptr), 16, 0, 0)

// ---------------- transpose ----------------
__global__ void tkern(const float* __restrict__ src, float* __restrict__ dst,
                      int R, int C) {
    __shared__ float t[32][33];
    int c = blockIdx.x * 32 + threadIdx.x;
    int r = blockIdx.y * 32 + threadIdx.y;
    if (r < R && c < C) t[threadIdx.y][threadIdx.x] = src[(size_t)r * C + c];
    __syncthreads();
    int rr = blockIdx.x * 32 + threadIdx.y;
    int cc = blockIdx.y * 32 + threadIdx.x;
    if (rr < C && cc < R) dst[(size_t)rr * R + cc] = t[threadIdx.x][threadIdx.y];
}

// ---------------- fold: W2x[plane][tap][d][512c] fp16 hi/lo ----------------
__global__ __launch_bounds__(256) void fold5_k(const float* __restrict__ conv_w,
                                               const float* __restrict__ lwT,
                                               _Float16* __restrict__ W2x) {
    int e0 = blockIdx.x * 8;
    int d = threadIdx.x;
    float acc[8];
    #pragma unroll
    for (int j = 0; j < 8; ++j) acc[j] = 0.f;
    for (int co = 0; co < 256; ++co) {
        float lw = lwT[co * 256 + d];
        const float* cwr = conv_w + (size_t)co * E_ + e0;   // wave-uniform
        #pragma unroll
        for (int j = 0; j < 8; ++j) acc[j] += cwr[j] * lw;
    }
    #pragma unroll
    for (int j = 0; j < 8; ++j) {
        int e = e0 + j;
        int c = e / 9, t9 = e - c * 9;
        _Float16 h = (_Float16)acc[j];
        _Float16 l = (_Float16)(acc[j] - (float)h);
        W2x[((size_t)(t9 * 256 + d)) * 512 + c] = h;
        W2x[((size_t)((9 + t9) * 256 + d)) * 512 + c] = l;
    }
}

__global__ void bias_k(const float* __restrict__ lwT, const float* __restrict__ conv_b,
                       const float* __restrict__ lin_b, float* __restrict__ b2) {
    int d = threadIdx.x;
    float acc = lin_b[d];
    for (int co = 0; co < 256; ++co) acc += lwT[co * 256 + d] * conv_b[co];
    b2[d] = acc;
}

__global__ void embsq_k(const float* __restrict__ emb, float* __restrict__ esq) {
    int w = threadIdx.x >> 6, lane = threadIdx.x & 63;
    int k = blockIdx.x * 4 + w;
    const float* row = emb + (size_t)k * 256;
    float s = 0.f;
    #pragma unroll
    for (int i = 0; i < 4; ++i) { float v = row[lane + 64 * i]; s += v * v; }
    #pragma unroll
    for (int m = 32; m >= 1; m >>= 1) s += __shfl_xor(s, m, 64);
    if (lane == 0) esq[k] = s;
}

// ---------------- latent -> channel-last fp16 hi/lo planes ----------------
__global__ __launch_bounds__(256) void packlat_k(const float* __restrict__ lat,
                                                 _Float16* __restrict__ Xnp) {
    int b = blockIdx.x, t = threadIdx.x;
    __shared__ float lt[128][65];
    const float* src = lat + (size_t)b * 512 * 64;
    _Float16* dst = Xnp + (size_t)b * 64 * 1024;
    for (int c0 = 0; c0 < 512; c0 += 128) {
        __syncthreads();
        #pragma unroll
        for (int j = 0; j < 8; ++j) {
            int f4 = t + j * 256;
            int cc = f4 >> 4, p4 = (f4 & 15) * 4;
            float4 v = *(const float4*)(src + (size_t)(c0 + cc) * 64 + p4);
            lt[cc][p4] = v.x; lt[cc][p4 + 1] = v.y;
            lt[cc][p4 + 2] = v.z; lt[cc][p4 + 3] = v.w;
        }
        __syncthreads();
        int pix = t >> 2, cr = (t & 3) * 32;
        #pragma unroll
        for (int q = 0; q < 4; ++q) {
            half8_t hh, ll;
            #pragma unroll
            for (int j = 0; j < 8; ++j) {
                float v = lt[cr + q * 8 + j][pix];
                _Float16 h = (_Float16)v;
                hh[j] = h; ll[j] = (_Float16)(v - (float)h);
            }
            *(half8_t*)(dst + (size_t)pix * 1024 + c0 + cr + q * 8) = hh;
            *(half8_t*)(dst + (size_t)pix * 1024 + 512 + c0 + cr + q * 8) = ll;
        }
    }
}

// ---------------- conv MFMA v4: slot-permuted, 3-segs-per-staging ----------
// grid (128 m-tiles, 2 n-tiles), 256 thr = 4 waves (2x2 of 64x64).
// LDS 64 KB: 2 bufs x {Ah,Al,Bh,Bl} x 8 KB (tiles 128 rows x 32 halves).
__global__ __launch_bounds__(256) void convm4_k(
    const _Float16* __restrict__ Xnp, const _Float16* __restrict__ W2x,
    const float* __restrict__ b2, const _Float16* __restrict__ zp,
    float* __restrict__ yb) {
    __shared__ char sm[65536];
    int m0 = blockIdx.x * 128, n0 = blockIdx.y * 128;
    int tid = threadIdx.x, w = tid >> 6, lane = tid & 63;
    int wm = w & 1, wn = w >> 1;
    int fr = lane & 15, fq = lane >> 4;

    // fragment-read byte offsets (slot-permuted layout), hoisted
    int xq = (fq ^ ((fr >> 1) & 3)) << 4;
    int aoff[4], boff[4];
    #pragma unroll
    for (int i = 0; i < 4; ++i) {
        aoff[i] = (wm * 64 + i * 16 + fr) * 64 + xq;
        boff[i] = (wn * 64 + i * 16 + fr) * 64 + xq;
    }
    // staging slot geometry (2 GLOADs per tile per wave)
    int slt[2], sr[2], sq[2];
    #pragma unroll
    for (int i = 0; i < 2; ++i) {
        int s = w * 128 + i * 64 + lane;
        slt[i] = s;
        sr[i] = s >> 2;
        sq[i] = ((s & 3) ^ ((s >> 3) & 3)) * 8;
    }

    f32x4 acc[4][4];
    #pragma unroll
    for (int s = 0; s < 4; ++s)
        #pragma unroll
        for (int t = 0; t < 4; ++t)
            #pragma unroll
            for (int r = 0; r < 4; ++r) acc[s][t][r] = 0.f;

    auto stage = [&](int it, int buf) {
        int tap = it >> 4, cc = it & 15;
        int dy = tap / 3 - 1, dx = tap - (tap / 3) * 3 - 1;
        char* L = sm + buf * 32768;
        #pragma unroll
        for (int i = 0; i < 2; ++i) {
            int choff = cc * 32 + sq[i];
            // A rows: shifted pixels with zero-page halo
            int gm = m0 + sr[i];
            int img = gm >> 6, pix = gm & 63;
            int ih = (pix >> 3) + dy, iw = (pix & 7) + dx;
            bool v = ((unsigned)ih < 8u) && ((unsigned)iw < 8u);
            const _Float16* a0 = v
                ? Xnp + ((size_t)(img * 64 + ih * 8 + iw)) * 1024 : zp;
            const _Float16* a1 = v ? a0 + 512 : zp;
            GLOAD_LDS16(a0 + choff, L + slt[i] * 16);
            GLOAD_LDS16(a1 + choff, L + 8192 + slt[i] * 16);
            // B rows (weights): hi plane tap, lo plane 9+tap
            const _Float16* bb =
                W2x + ((size_t)(tap * 256 + n0 + sr[i])) * 512 + choff;
            GLOAD_LDS16(bb, L + 16384 + slt[i] * 16);
            GLOAD_LDS16(bb + (size_t)9 * 256 * 512, L + 24576 + slt[i] * 16);
        }
    };

    stage(0, 0);
    for (int it = 0; it < 144; ++it) {
        __syncthreads();
        if (it + 1 < 144) stage(it + 1, (it + 1) & 1);
        const char* L = sm + (it & 1) * 32768;
        half8_t ah[4], al[4], bh[4], bl[4];
        #pragma unroll
        for (int s = 0; s < 4; ++s) ah[s] = *(const half8_t*)(L + aoff[s]);
        #pragma unroll
        for (int t = 0; t < 4; ++t) bh[t] = *(const half8_t*)(L + 16384 + boff[t]);
        #pragma unroll
        for (int s = 0; s < 4; ++s)
            #pragma unroll
            for (int t = 0; t < 4; ++t)
                acc[s][t] = __builtin_amdgcn_mfma_f32_16x16x32_f16(
                    ah[s], bh[t], acc[s][t], 0, 0, 0);
        #pragma unroll
        for (int t = 0; t < 4; ++t) bl[t] = *(const half8_t*)(L + 24576 + boff[t]);
        #pragma unroll
        for (int s = 0; s < 4; ++s)
            #pragma unroll
            for (int t = 0; t < 4; ++t)
                acc[s][t] = __builtin_amdgcn_mfma_f32_16x16x32_f16(
                    ah[s], bl[t], acc[s][t], 0, 0, 0);
        #pragma unroll
        for (int s = 0; s < 4; ++s) al[s] = *(const half8_t*)(L + 8192 + aoff[s]);
        #pragma unroll
        for (int s = 0; s < 4; ++s)
            #pragma unroll
            for (int t = 0; t < 4; ++t)
                acc[s][t] = __builtin_amdgcn_mfma_f32_16x16x32_f16(
                    al[s], bh[t], acc[s][t], 0, 0, 0);
    }

    float bv[4];
    #pragma unroll
    for (int t = 0; t < 4; ++t) bv[t] = b2[n0 + wn * 64 + t * 16 + fr];
    #pragma unroll
    for (int s = 0; s < 4; ++s)
        #pragma unroll
        for (int r = 0; r < 4; ++r) {
            int m = m0 + wm * 64 + s * 16 + fq * 4 + r;
            #pragma unroll
            for (int t = 0; t < 4; ++t) {
                int d = n0 + wn * 64 + t * 16 + fr;
                yb[(size_t)m * 256 + d] = acc[s][t][r] + bv[t];
            }
        }
}

// ---------------- fp32 -> fp16 hi pack ----------------
__global__ void packhi_k(const float* __restrict__ x, _Float16* __restrict__ o) {
    int i = blockIdx.x * 256 + threadIdx.x;
    float4 v = *(const float4*)(x + (size_t)i * 4);
    half4_t h = {(_Float16)v.x, (_Float16)v.y, (_Float16)v.z, (_Float16)v.w};
    *(half4_t*)(o + (size_t)i * 4) = h;
}

// ---------------- MFMA screen v4: BK=64, slot-permuted, dbuf ----------------
// grid (128 m-tiles, 64 n-tiles), 256 thr = 4 waves (2x2 of 64x64).
// LDS 64 KB: 2 bufs x {A,B} x 16 KB (tiles 128 rows x 64 halves).
__global__ __launch_bounds__(256) void screen4_k(
    const _Float16* __restrict__ A2, const _Float16* __restrict__ B2,
    const float* __restrict__ esq, float* __restrict__ ps2, int* __restrict__ pi2) {
    __shared__ char sm[65536];
    int m0 = blockIdx.x * 128, n0 = blockIdx.y * 128;
    int tid = threadIdx.x, w = tid >> 6, lane = tid & 63;
    int wm = w & 1, wn = w >> 1;
    int fr = lane & 15, fq = lane >> 4;

    int xq8[2];
    #pragma unroll
    for (int kk = 0; kk < 2; ++kk) xq8[kk] = ((kk * 4 + fq) ^ (fr & 7)) << 4;
    int arow[4], brow[4];
    #pragma unroll
    for (int i = 0; i < 4; ++i) {
        arow[i] = (wm * 64 + i * 16 + fr) * 128;
        brow[i] = (wn * 64 + i * 16 + fr) * 128;
    }
    int slt[4], sr[4], sq[4];
    #pragma unroll
    for (int i = 0; i < 4; ++i) {
        int s = w * 256 + i * 64 + lane;
        slt[i] = s;
        sr[i] = s >> 3;
        sq[i] = ((s & 7) ^ ((s >> 3) & 7)) * 8;
    }

    auto stage = [&](int kt, int buf) {
        char* L = sm + buf * 32768;
        int ko = kt * 64;
        #pragma unroll
        for (int i = 0; i < 4; ++i) {
            GLOAD_LDS16(A2 + (size_t)(m0 + sr[i]) * 256 + ko + sq[i],
                        L + slt[i] * 16);
            GLOAD_LDS16(B2 + (size_t)(n0 + sr[i]) * 256 + ko + sq[i],
                        L + 16384 + slt[i] * 16);
        }
    };

    f32x4 acc[4][4];
    #pragma unroll
    for (int s = 0; s < 4; ++s)
        #pragma unroll
        for (int t = 0; t < 4; ++t)
            #pragma unroll
            for (int r = 0; r < 4; ++r) acc[s][t][r] = 0.f;

    stage(0, 0);
    for (int kt = 0; kt < 4; ++kt) {
        __syncthreads();
        if (kt + 1 < 4) stage(kt + 1, (kt + 1) & 1);
        const char* L = sm + (kt & 1) * 32768;
        #pragma unroll
        for (int kk = 0; kk < 2; ++kk) {
            half8_t af[4], bf[4];
            #pragma unroll
            for (int s = 0; s < 4; ++s)
                af[s] = *(const half8_t*)(L + arow[s] + xq8[kk]);
            #pragma unroll
            for (int t = 0; t < 4; ++t)
                bf[t] = *(const half8_t*)(L + 16384 + brow[t] + xq8[kk]);
            #pragma unroll
            for (int s = 0; s < 4; ++s)
                #pragma unroll
                for (int t = 0; t < 4; ++t)
                    acc[s][t] = __builtin_amdgcn_mfma_f32_16x16x32_f16(
                        af[s], bf[t], acc[s][t], 0, 0, 0);
        }
    }

    float esv[4];
    #pragma unroll
    for (int t = 0; t < 4; ++t) esv[t] = esq[n0 + wn * 64 + t * 16 + fr];
    int colIdx = blockIdx.y * 2 + wn;
    #pragma unroll
    for (int s = 0; s < 4; ++s) {
        #pragma unroll
        for (int r = 0; r < 4; ++r) {
            float best = 3.4e38f; int bidx = 0x7fffffff;
            #pragma unroll
            for (int t = 0; t < 4; ++t) {
                float sc = esv[t] - 2.f * acc[s][t][r];
                int k = n0 + wn * 64 + t * 16 + fr;
                if (sc < best || (sc == best && k < bidx)) { best = sc; bidx = k; }
            }
            #pragma unroll
            for (int msk = 1; msk <= 8; msk <<= 1) {
                float so = __shfl_xor(best, msk, 64);
                int ko2 = __shfl_xor(bidx, msk, 64);
                if (so < best || (so == best && ko2 < bidx)) { best = so; bidx = ko2; }
            }
            if (fr == 0) {
                int m = m0 + wm * 64 + s * 16 + fq * 4 + r;
                ps2[(size_t)m * 128 + colIdx] = best;
                pi2[(size_t)m * 128 + colIdx] = bidx;
            }
        }
    }
}

// ---------------- exact fp32 refine ----------------
__global__ __launch_bounds__(256) void refine2_k(
    const float* __restrict__ y, const float* __restrict__ emb,
    const float* __restrict__ esq, const float* __restrict__ ps2,
    const int* __restrict__ pi2, int* __restrict__ out) {
    int lane = threadIdx.x & 63;
    int m = blockIdx.x * 4 + (threadIdx.x >> 6);
    float4 yv = *(const float4*)(y + (size_t)m * 256 + lane * 4);
    float sc_[2]; int kc_[2];
    #pragma unroll
    for (int i = 0; i < 2; ++i) {
        sc_[i] = ps2[(size_t)m * 128 + lane * 2 + i];
        kc_[i] = pi2[(size_t)m * 128 + lane * 2 + i];
    }
    float s0 = fminf(sc_[0], sc_[1]);
    #pragma unroll
    for (int msk = 1; msk <= 32; msk <<= 1) s0 = fminf(s0, __shfl_xor(s0, msk, 64));
    float thr = s0 + 0.25f;
    float best = 3.4e38f; int bk = 0x7fffffff;
    for (int c = 0; c < 128; ++c) {
        float scc = __shfl(sc_[c & 1], c >> 1, 64);
        if (scc <= thr) {            // wave-uniform
            int k = __shfl(kc_[c & 1], c >> 1, 64);
            float4 ev = *(const float4*)(emb + (size_t)k * 256 + lane * 4);
            float d = yv.x * ev.x + yv.y * ev.y + yv.z * ev.z + yv.w * ev.w;
            #pragma unroll
            for (int msk = 1; msk <= 32; msk <<= 1) d += __shfl_xor(d, msk, 64);
            float sx = esq[k] - 2.f * d;
            if (sx < best || (sx == best && k < bk)) { best = sx; bk = k; }
        }
    }
    if (lane == 0) out[m] = bk;
}

extern "C" void kernel_launch(void* const* d_in, const int* in_sizes, int n_in,
                              void* d_out, int out_size, void* d_ws, size_t ws_size,
                              hipStream_t stream) {
    const float* latent = (const float*)d_in[0];
    const float* conv_w = (const float*)d_in[1];
    const float* conv_b = (const float*)d_in[2];
    const float* lin_w  = (const float*)d_in[3];
    const float* lin_b  = (const float*)d_in[4];
    const float* emb    = (const float*)d_in[5];
    int* out = (int*)d_out;

    char* W = (char*)d_ws;                           // proven 55.35 MB budget
    float*    lwT = (float*)(W + 0);                 //   262,144
    float*    b2  = (float*)(W + 262144);            //     1,024
    float*    esq = (float*)(W + 263168);            //    32,768
    float*    yb  = (float*)(W + 295936);            // 16,777,216
    _Float16* W2x = (_Float16*)(W + 17073152);       //  4,718,592
    _Float16* zp  = (_Float16*)(W + 21791744);       //     1,024
    _Float16* Xnp = (_Float16*)(W + 21792768);       // 33,554,432 (conv-time)
    // post-conv aliases on the Xnp region:
    _Float16* A2  = (_Float16*)(W + 21792768);       //  8,388,608
    _Float16* B2  = (_Float16*)(W + 30181376);       //  4,194,304
    float*    ps2 = (float*)(W + 34375680);          //  8,388,608
    int*      pi2 = (int*)(W + 42764288);            //  8,388,608 -> 51,152,896

    dim3 t32(32, 32);
    tkern<<<dim3(8, 8), t32, 0, stream>>>(lin_w, lwT, 256, 256);
    bias_k<<<1, 256, 0, stream>>>(lwT, conv_b, lin_b, b2);
    embsq_k<<<2048, 256, 0, stream>>>(emb, esq);
    fold5_k<<<576, 256, 0, stream>>>(conv_w, lwT, W2x);
    hipMemsetAsync(zp, 0, 1024, stream);
    packlat_k<<<256, 256, 0, stream>>>(latent, Xnp);

    convm4_k<<<dim3(128, 2), 256, 0, stream>>>(Xnp, W2x, b2, zp, yb);

    packhi_k<<<4096, 256, 0, stream>>>(yb, A2);      // after conv: A2 aliases Xnp
    packhi_k<<<2048, 256, 0, stream>>>(emb, B2);
    screen4_k<<<dim3(128, 64), 256, 0, stream>>>(A2, B2, esq, ps2, pi2);
    refine2_k<<<4096, 256, 0, stream>>>(yb, emb, esq, ps2, pi2, out);
}